// Round 14
// baseline (804.822 us; speedup 1.0000x reference)
//
#include <hip/hip_runtime.h>
#include <hip/hip_bf16.h>

#define F_IN 512
#define H_DIM 256
#define C_DIM 64
#define K_STEPS 10
#define ALPHA 0.1f

typedef __attribute__((ext_vector_type(8))) short bf16x8;
typedef __attribute__((ext_vector_type(4))) float f32x4;

static __device__ __forceinline__ ushort f2bf(float f) {
    __hip_bfloat16 b = __float2bfloat16(f);
    return *(ushort*)&b;
}
static __device__ __forceinline__ float bflo(unsigned int w) {
    union { unsigned int i; float f; } v; v.i = w << 16; return v.f;
}
static __device__ __forceinline__ float bfhi(unsigned int w) {
    union { unsigned int i; float f; } v; v.i = w & 0xffff0000u; return v.f;
}

#define ACC8(u) do { \
    acc[0] += bflo(u.x); acc[1] += bfhi(u.x); \
    acc[2] += bflo(u.y); acc[3] += bfhi(u.y); \
    acc[4] += bflo(u.z); acc[5] += bfhi(u.z); \
    acc[6] += bflo(u.w); acc[7] += bfhi(u.w); } while (0)

// ---------------------------------------------------------------------------
// Prep: W1/W2 -> fragment-major bf16 + zero cnt.
// ---------------------------------------------------------------------------
__global__ void prep_kernel(const float* __restrict__ W1, ushort* __restrict__ W1p,
                            const float* __restrict__ W2, ushort* __restrict__ W2p,
                            int* __restrict__ cnt, int n)
{
    const int o = blockIdx.x * 256 + threadIdx.x;
    {   // W1p: o in [0, 131072)
        const int j = o & 7;
        const int l = (o >> 3) & 63;
        const int b = o >> 9;          // 0..255
        const int f = b & 15, ks = b >> 4;
        const int k = ks * 32 + (l >> 4) * 8 + j;
        const int col = f * 16 + (l & 15);
        W1p[o] = f2bf(W1[k * H_DIM + col]);
    }
    if (o < 16384) {
        const int j = o & 7;
        const int l = (o >> 3) & 63;
        const int b = o >> 9;          // 0..31
        const int f = b & 3, kk = b >> 2;
        const int k = kk * 32 + (l >> 4) * 8 + j;
        const int col = f * 16 + (l & 15);
        W2p[o] = f2bf(W2[k * C_DIM + col]);
    }
    if (o < n) cnt[o] = 0;
}

// ---------------------------------------------------------------------------
// FUSED MLP + rank, 3:1 block ratio. Blocks with (b&3)==3 run the atomic rank
// pass (24 edges/thread); the rest run the MFMA MLP (writes f32 hf).
// MLP role is barrier-free (per-wave h1 tile); x is prefetched 4 steps deep
// in a rotating register file, pinned above the MFMAs by sched_barrier(0).
// ---------------------------------------------------------------------------
__global__ __launch_bounds__(256) void mlp_rank_kernel(
    const float* __restrict__ x,
    const ushort* __restrict__ W1p, const float* __restrict__ b1,
    const ushort* __restrict__ W2p, const float* __restrict__ b2,
    float* __restrict__ hf, int n,
    const int* __restrict__ col, int* __restrict__ cnt,
    int* __restrict__ rank, int e)
{
    __shared__ __align__(16) char smem[32768];   // 4 x 8KB per-wave h1 tiles

    if ((blockIdx.x & 3) == 3) {
        // ---- rank role: 24 edges (3 int4-pairs) per thread ----
        const int base = ((blockIdx.x >> 2) * 256 + threadIdx.x) * 24;
        #pragma unroll
        for (int g = 0; g < 3; ++g) {
            const int i0 = base + g * 8;
            if (i0 + 7 < e) {
                const int4 ca = *(const int4*)&col[i0];
                const int4 cb = *(const int4*)&col[i0 + 4];
                const int r0 = atomicAdd(&cnt[ca.x], 1);
                const int r1 = atomicAdd(&cnt[ca.y], 1);
                const int r2 = atomicAdd(&cnt[ca.z], 1);
                const int r3 = atomicAdd(&cnt[ca.w], 1);
                const int r4 = atomicAdd(&cnt[cb.x], 1);
                const int r5 = atomicAdd(&cnt[cb.y], 1);
                const int r6 = atomicAdd(&cnt[cb.z], 1);
                const int r7 = atomicAdd(&cnt[cb.w], 1);
                *(int4*)&rank[i0]     = make_int4(r0, r1, r2, r3);
                *(int4*)&rank[i0 + 4] = make_int4(r4, r5, r6, r7);
            } else if (i0 < e) {
                for (int i = i0; i < e; ++i) rank[i] = atomicAdd(&cnt[col[i]], 1);
            }
        }
        return;
    }

    // ---- MLP role: bx = dense index over blocks with (b&3)!=3 ----
    const int bx = (blockIdx.x >> 2) * 3 + (blockIdx.x & 3);
    const int t = threadIdx.x;
    const int lane = t & 63;
    const int wv = t >> 6;
    const int ln15 = lane & 15;
    const int hi = lane >> 4;
    const long row0 = (long)bx * 64 + wv * 16;

    long arow = row0 + ln15;
    if (arow > (long)n - 1) arow = n - 1;
    const float4* xp = (const float4*)(x + arow * F_IN);

    f32x4 acc[16];
    #pragma unroll
    for (int f = 0; f < 16; ++f) acc[f] = (f32x4){0.f, 0.f, 0.f, 0.f};

    // 4-deep rotating x prefetch (static indices via full unroll)
    float4 xb[4][2];
    #pragma unroll
    for (int i = 0; i < 4; ++i) {
        xb[i][0] = xp[i * 8 + hi * 2];
        xb[i][1] = xp[i * 8 + hi * 2 + 1];
    }

    #pragma unroll
    for (int ks = 0; ks < 16; ++ks) {
        const int sl = ks & 3;
        const float4 a0 = xb[sl][0];
        const float4 a1 = xb[sl][1];
        if (ks + 4 < 16) {   // refill the freed slot, 4 steps ahead
            xb[sl][0] = xp[(ks + 4) * 8 + hi * 2];
            xb[sl][1] = xp[(ks + 4) * 8 + hi * 2 + 1];
        }
        // pin: prefetch issues stay ABOVE the MFMA cluster (prevents sinking)
        __builtin_amdgcn_sched_barrier(0);

        bf16x8 af;
        af[0] = (short)f2bf(a0.x); af[1] = (short)f2bf(a0.y);
        af[2] = (short)f2bf(a0.z); af[3] = (short)f2bf(a0.w);
        af[4] = (short)f2bf(a1.x); af[5] = (short)f2bf(a1.y);
        af[6] = (short)f2bf(a1.z); af[7] = (short)f2bf(a1.w);
        const ushort* wb = W1p + (long)ks * 8192 + lane * 8;
        #pragma unroll
        for (int f = 0; f < 16; ++f) {
            const bf16x8 bfv = *(const bf16x8*)(wb + f * 512);
            acc[f] = __builtin_amdgcn_mfma_f32_16x16x32_bf16(af, bfv, acc[f], 0, 0, 0);
        }
    }

    // h1 = relu(acc + b1) -> per-wave swizzled LDS tile (no cross-wave access)
    char* hreg = smem + wv * 8192;
    #pragma unroll
    for (int f = 0; f < 16; ++f) {
        const int c = f * 16 + ln15;
        const float bias = b1[c];
        #pragma unroll
        for (int v = 0; v < 4; ++v) {
            const int r = hi * 4 + v;
            float val = acc[f][v] + bias;
            val = val > 0.f ? val : 0.f;
            const int pos = (r * 256 + c) * 2;
            *(short*)(hreg + (pos ^ ((r & 7) << 4))) = (short)f2bf(val);
        }
    }

    // GEMM2: [16x256] @ [256x64]  (same-wave data; no barrier needed)
    f32x4 acc2[4];
    #pragma unroll
    for (int f = 0; f < 4; ++f) acc2[f] = (f32x4){0.f, 0.f, 0.f, 0.f};
    #pragma unroll
    for (int kk = 0; kk < 8; ++kk) {
        const int pos = (ln15 * 256 + kk * 32 + hi * 8) * 2;
        const bf16x8 a2 = *(const bf16x8*)(hreg + (pos ^ ((ln15 & 7) << 4)));
        #pragma unroll
        for (int f = 0; f < 4; ++f) {
            const bf16x8 b2f = *(const bf16x8*)&W2p[(kk * 4 + f) * 512 + lane * 8];
            acc2[f] = __builtin_amdgcn_mfma_f32_16x16x32_bf16(a2, b2f, acc2[f], 0, 0, 0);
        }
    }

    #pragma unroll
    for (int f = 0; f < 4; ++f) {
        const int c = f * 16 + ln15;
        const float bias = b2[c];
        #pragma unroll
        for (int v = 0; v < 4; ++v) {
            const long r = row0 + hi * 4 + v;
            if (r < n) hf[r * C_DIM + c] = acc2[f][v] + bias;
        }
    }
}

// ---------------------------------------------------------------------------
// Scan (1024 elems/block) + dinv fused
// ---------------------------------------------------------------------------
__global__ __launch_bounds__(256) void scan1_kernel(
    const int* __restrict__ cnt, int* __restrict__ rowptr, int* __restrict__ sums,
    float* __restrict__ dinv, int n)
{
    __shared__ int lds[256];
    const int t = threadIdx.x;
    const int base = blockIdx.x * 1024 + t * 4;
    int v[4];
    #pragma unroll
    for (int j = 0; j < 4; ++j) v[j] = (base + j < n) ? cnt[base + j] : 0;
    const int tsum = v[0] + v[1] + v[2] + v[3];
    lds[t] = tsum;
    __syncthreads();
    for (int o = 1; o < 256; o <<= 1) {
        const int add = (t >= o) ? lds[t - o] : 0;
        __syncthreads();
        lds[t] += add;
        __syncthreads();
    }
    int run = lds[t] - tsum;
    #pragma unroll
    for (int j = 0; j < 4; ++j) {
        if (base + j < n) {
            rowptr[base + j] = run;
            dinv[base + j] = rsqrtf((float)v[j] + 1.0f);   // +1 self-loop
        }
        run += v[j];
    }
    if (t == 255) sums[blockIdx.x] = lds[255];
}

__global__ __launch_bounds__(128) void scan2_kernel(int* __restrict__ sums, int nc)
{
    __shared__ int lds[128];
    const int t = threadIdx.x;
    const int v = (t < nc) ? sums[t] : 0;
    lds[t] = v;
    __syncthreads();
    for (int o = 1; o < 128; o <<= 1) {
        const int add = (t >= o) ? lds[t - o] : 0;
        __syncthreads();
        lds[t] += add;
        __syncthreads();
    }
    if (t < nc) sums[t] = lds[t] - v;
}

__global__ void scan3_kernel(int* __restrict__ rowptr, const int* __restrict__ sums, int n, int e)
{
    int i = blockIdx.x * 256 + threadIdx.x;
    if (i < n) rowptr[i] += sums[i >> 10];
    else if (i == n) rowptr[n] = e;
}

// ---------------------------------------------------------------------------
// FUSED fill (atomic-free, 8-edge ILP) + zsinit. Role by block range.
// ---------------------------------------------------------------------------
__global__ void fill_zs_kernel(const int* __restrict__ row, const int* __restrict__ col,
                               const int* __restrict__ rowptr, const int* __restrict__ rank,
                               int* __restrict__ csr_src, int e, int fill_blocks,
                               const float* __restrict__ hf, const float* __restrict__ dinv,
                               ushort* __restrict__ ah, ushort* __restrict__ zs, int n)
{
    if ((int)blockIdx.x < fill_blocks) {
        const int i0 = (blockIdx.x * 256 + threadIdx.x) * 8;
        if (i0 + 7 < e) {
            const int4 ca  = *(const int4*)&col[i0];
            const int4 cb  = *(const int4*)&col[i0 + 4];
            const int4 ka  = *(const int4*)&rank[i0];
            const int4 kb  = *(const int4*)&rank[i0 + 4];
            const int4 ra  = *(const int4*)&row[i0];
            const int4 rb  = *(const int4*)&row[i0 + 4];
            csr_src[rowptr[ca.x] + ka.x] = ra.x;
            csr_src[rowptr[ca.y] + ka.y] = ra.y;
            csr_src[rowptr[ca.z] + ka.z] = ra.z;
            csr_src[rowptr[ca.w] + ka.w] = ra.w;
            csr_src[rowptr[cb.x] + kb.x] = rb.x;
            csr_src[rowptr[cb.y] + kb.y] = rb.y;
            csr_src[rowptr[cb.z] + kb.z] = rb.z;
            csr_src[rowptr[cb.w] + kb.w] = rb.w;
        } else if (i0 < e) {
            for (int i = i0; i < e; ++i) csr_src[rowptr[col[i]] + rank[i]] = row[i];
        }
        return;
    }
    // zsinit role: 8 channels per thread
    const int i = ((int)blockIdx.x - fill_blocks) * 256 + threadIdx.x;
    if (i >= n * 8) return;
    const int node = i >> 3, part = i & 7;
    const float di = dinv[node];
    const long off = (long)node * C_DIM + part * 8;
    const float4 a = *(const float4*)&hf[off];
    const float4 b = *(const float4*)&hf[off + 4];
    uint4 z, ua;
    z.x = ((unsigned)f2bf(a.y * di) << 16) | f2bf(a.x * di);
    z.y = ((unsigned)f2bf(a.w * di) << 16) | f2bf(a.z * di);
    z.z = ((unsigned)f2bf(b.y * di) << 16) | f2bf(b.x * di);
    z.w = ((unsigned)f2bf(b.w * di) << 16) | f2bf(b.z * di);
    ua.x = ((unsigned)f2bf(a.y * ALPHA) << 16) | f2bf(a.x * ALPHA);
    ua.y = ((unsigned)f2bf(a.w * ALPHA) << 16) | f2bf(a.z * ALPHA);
    ua.z = ((unsigned)f2bf(b.y * ALPHA) << 16) | f2bf(b.x * ALPHA);
    ua.w = ((unsigned)f2bf(b.w * ALPHA) << 16) | f2bf(b.z * ALPHA);
    *(uint4*)&zs[off] = z;
    *(uint4*)&ah[off] = ua;
}

// ---------------------------------------------------------------------------
// APPNP step (round-8 proven): one wave per node; slot s = lane>>3 (8 slots x
// 16B), guarded 4-deep row pipeline. Final iteration fuses log-softmax.
// ---------------------------------------------------------------------------
__global__ __launch_bounds__(256) void gather8_kernel(
    const int* __restrict__ rowptr, const int* __restrict__ csr_src,
    const float* __restrict__ dinv, const ushort* __restrict__ ah,
    const ushort* __restrict__ zs_in, ushort* __restrict__ zs_out,
    float* __restrict__ out, int n, int final_it)
{
    const int node = (blockIdx.x * 256 + threadIdx.x) >> 6;
    if (node >= n) return;
    const int lane = threadIdx.x & 63;
    const int s = lane >> 3;
    const int cg = lane & 7;

    const int p0 = rowptr[node];
    const int p1 = rowptr[node + 1];

    float acc[8];
    #pragma unroll
    for (int c = 0; c < 8; ++c) acc[c] = 0.f;

    if (s == 0) {  // self-loop: 8 lanes cover own 128B row
        const uint4 u = *(const uint4*)&zs_in[(long)node * C_DIM + cg * 8];
        ACC8(u);
    }

    if (p0 < p1) {
        int p = p0 + s;
        int c0 = (p      < p1) ? csr_src[p]      : -1;
        int c1 = (p +  8 < p1) ? csr_src[p +  8] : -1;
        int c2 = (p + 16 < p1) ? csr_src[p + 16] : -1;
        int c3 = (p + 24 < p1) ? csr_src[p + 24] : -1;
        while (c0 >= 0) {
            uint4 u0, u1, u2, u3;
            u0 = *(const uint4*)&zs_in[(long)c0 * C_DIM + cg * 8];
            if (c1 >= 0) u1 = *(const uint4*)&zs_in[(long)c1 * C_DIM + cg * 8];
            if (c2 >= 0) u2 = *(const uint4*)&zs_in[(long)c2 * C_DIM + cg * 8];
            if (c3 >= 0) u3 = *(const uint4*)&zs_in[(long)c3 * C_DIM + cg * 8];
            p += 32;
            const int n0 = (p      < p1) ? csr_src[p]      : -1;
            const int n1 = (p +  8 < p1) ? csr_src[p +  8] : -1;
            const int n2 = (p + 16 < p1) ? csr_src[p + 16] : -1;
            const int n3 = (p + 24 < p1) ? csr_src[p + 24] : -1;
            ACC8(u0);
            if (c1 >= 0) ACC8(u1);
            if (c2 >= 0) ACC8(u2);
            if (c3 >= 0) ACC8(u3);
            c0 = n0; c1 = n1; c2 = n2; c3 = n3;
        }
    }

    #pragma unroll
    for (int c = 0; c < 8; ++c) {
        acc[c] += __shfl_xor(acc[c], 8, 64);
        acc[c] += __shfl_xor(acc[c], 16, 64);
        acc[c] += __shfl_xor(acc[c], 32, 64);
    }

    if (s == 0) {
        const float di = dinv[node];
        const long off = (long)node * C_DIM + cg * 8;
        const uint4 ua = *(const uint4*)&ah[off];
        const float w = (1.0f - ALPHA) * di;
        float z[8];
        z[0] = w * acc[0] + bflo(ua.x);
        z[1] = w * acc[1] + bfhi(ua.x);
        z[2] = w * acc[2] + bflo(ua.y);
        z[3] = w * acc[3] + bfhi(ua.y);
        z[4] = w * acc[4] + bflo(ua.z);
        z[5] = w * acc[5] + bfhi(ua.z);
        z[6] = w * acc[6] + bflo(ua.w);
        z[7] = w * acc[7] + bfhi(ua.w);
        if (!final_it) {
            uint4 o;
            o.x = ((unsigned)f2bf(z[1] * di) << 16) | f2bf(z[0] * di);
            o.y = ((unsigned)f2bf(z[3] * di) << 16) | f2bf(z[2] * di);
            o.z = ((unsigned)f2bf(z[5] * di) << 16) | f2bf(z[4] * di);
            o.w = ((unsigned)f2bf(z[7] * di) << 16) | f2bf(z[6] * di);
            *(uint4*)&zs_out[off] = o;
        } else {
            // fused log-softmax across the 8 s==0 lanes of this node
            float m = z[0];
            #pragma unroll
            for (int j = 1; j < 8; ++j) m = fmaxf(m, z[j]);
            m = fmaxf(m, __shfl_xor(m, 1, 64));
            m = fmaxf(m, __shfl_xor(m, 2, 64));
            m = fmaxf(m, __shfl_xor(m, 4, 64));
            float se = 0.f;
            #pragma unroll
            for (int j = 0; j < 8; ++j) se += expf(z[j] - m);
            se += __shfl_xor(se, 1, 64);
            se += __shfl_xor(se, 2, 64);
            se += __shfl_xor(se, 4, 64);
            const float ls = m + logf(se);
            *(float4*)&out[off]     = make_float4(z[0] - ls, z[1] - ls, z[2] - ls, z[3] - ls);
            *(float4*)&out[off + 4] = make_float4(z[4] - ls, z[5] - ls, z[6] - ls, z[7] - ls);
        }
    }
}

// ---------------------------------------------------------------------------
extern "C" void kernel_launch(void* const* d_in, const int* in_sizes, int n_in,
                              void* d_out, int out_size, void* d_ws, size_t ws_size,
                              hipStream_t stream)
{
    const float* x  = (const float*)d_in[0];
    const int* ei   = (const int*)d_in[1];
    const float* W1 = (const float*)d_in[2];
    const float* b1 = (const float*)d_in[3];
    const float* W2 = (const float*)d_in[4];
    const float* b2 = (const float*)d_in[5];
    float* out = (float*)d_out;

    const int N = in_sizes[0] / F_IN;       // 100000
    const int E = in_sizes[1] / 2;          // 3200000
    const int* row = ei;                    // source
    const int* col = ei + E;                // target

    // workspace layout
    ushort* ah     = (ushort*)d_ws;                           // N*64 bf16 (alpha*h)
    ushort* zs_a   = ah + (size_t)N * C_DIM;                  // N*64 bf16
    ushort* zs_b   = zs_a + (size_t)N * C_DIM;                // N*64 bf16
    float*  hf     = (float*)(zs_b + (size_t)N * C_DIM);      // N*64 f32
    float*  dinv   = hf + (size_t)N * C_DIM;                  // N
    int*    cnt    = (int*)(dinv + N);                        // N
    int*    rowptr = cnt + N;                                 // N+16 (padded)
    int*    rank   = rowptr + N + 16;                         // E
    int*    csr_src = rank + E;                               // E (+4 pad)
    int*    sums   = csr_src + E + 4;                         // 128
    ushort* W1p    = (ushort*)(sums + 128);                   // 131072
    ushort* W2p    = W1p + 131072;                            // 16384

    const int mlp_blocks  = (N + 63) / 64;                    // 1563
    const int rank_blocks = (E + 24 * 256 - 1) / (24 * 256);  // 521
    // 3:1 interleave: need 4*max(ceil(mlp/3), rank_blocks) block groups
    const int groups = ((mlp_blocks + 2) / 3 > rank_blocks) ? (mlp_blocks + 2) / 3 : rank_blocks;
    const int fused_blocks = groups * 4;
    const int nchunks = (N + 1023) / 1024;

    // 1. weight prep + cnt zero
    prep_kernel<<<512, 256, 0, stream>>>(W1, W1p, W2, W2p, cnt, N);

    // 2. FUSED: MLP (3/4 of blocks, writes hf) || rank (1/4, atomics)
    mlp_rank_kernel<<<fused_blocks, 256, 0, stream>>>(x, W1p, b1, W2p, b2, hf, N,
                                                      col, cnt, rank, E);

    // 3. scans (dinv, rowptr)
    scan1_kernel<<<nchunks, 256, 0, stream>>>(cnt, rowptr, sums, dinv, N);
    scan2_kernel<<<1, 128, 0, stream>>>(sums, nchunks);
    scan3_kernel<<<(N + 256) / 256, 256, 0, stream>>>(rowptr, sums, N, E);

    // 4. FUSED: fill (atomic-free) || zsinit (ah, zs_a from hf)
    const int fill_blocks = (E / 8 + 255) / 256;
    const int zs_blocks = (N * 8 + 255) / 256;
    fill_zs_kernel<<<fill_blocks + zs_blocks, 256, 0, stream>>>(
        row, col, rowptr, rank, csr_src, E, fill_blocks,
        hf, dinv, ah, zs_a, N);

    // 5. APPNP iterations (ping-pong bf16; final fuses log-softmax -> out)
    const int gblk = (N + 3) / 4;   // one wave per node
    for (int it = 0; it < K_STEPS; ++it) {
        const ushort* in = (it & 1) ? zs_b : zs_a;
        ushort* outb     = (it & 1) ? zs_a : zs_b;
        gather8_kernel<<<gblk, 256, 0, stream>>>(rowptr, csr_src, dinv, ah,
                                                 in, outb, out, N,
                                                 it == K_STEPS - 1 ? 1 : 0);
    }
}

// Round 15
// 780.178 us; speedup vs baseline: 1.0316x; 1.0316x over previous
//
#include <hip/hip_runtime.h>
#include <hip/hip_bf16.h>

#define F_IN 512
#define H_DIM 256
#define C_DIM 64
#define K_STEPS 10
#define ALPHA 0.1f

typedef __attribute__((ext_vector_type(8))) short bf16x8;
typedef __attribute__((ext_vector_type(4))) float f32x4;

static __device__ __forceinline__ ushort f2bf(float f) {
    __hip_bfloat16 b = __float2bfloat16(f);
    return *(ushort*)&b;
}
static __device__ __forceinline__ float bflo(unsigned int w) {
    union { unsigned int i; float f; } v; v.i = w << 16; return v.f;
}
static __device__ __forceinline__ float bfhi(unsigned int w) {
    union { unsigned int i; float f; } v; v.i = w & 0xffff0000u; return v.f;
}

#define ACC8(u) do { \
    acc[0] += bflo(u.x); acc[1] += bfhi(u.x); \
    acc[2] += bflo(u.y); acc[3] += bfhi(u.y); \
    acc[4] += bflo(u.z); acc[5] += bfhi(u.z); \
    acc[6] += bflo(u.w); acc[7] += bfhi(u.w); } while (0)

// global_load_lds: 16B per lane, wave-uniform LDS base + lane*16
#define GLOAD_LDS16(gp, lp) __builtin_amdgcn_global_load_lds( \
    (const __attribute__((address_space(1))) unsigned int*)(gp), \
    (__attribute__((address_space(3))) unsigned int*)(lp), 16, 0, 0)

// ---------------------------------------------------------------------------
// Prep: W1/W2 -> fragment-major bf16 + zero cnt.
// ---------------------------------------------------------------------------
__global__ void prep_kernel(const float* __restrict__ W1, ushort* __restrict__ W1p,
                            const float* __restrict__ W2, ushort* __restrict__ W2p,
                            int* __restrict__ cnt, int n)
{
    const int o = blockIdx.x * 256 + threadIdx.x;
    {   // W1p: o in [0, 131072)
        const int j = o & 7;
        const int l = (o >> 3) & 63;
        const int b = o >> 9;          // 0..255
        const int f = b & 15, ks = b >> 4;
        const int k = ks * 32 + (l >> 4) * 8 + j;
        const int col = f * 16 + (l & 15);
        W1p[o] = f2bf(W1[k * H_DIM + col]);
    }
    if (o < 16384) {
        const int j = o & 7;
        const int l = (o >> 3) & 63;
        const int b = o >> 9;          // 0..31
        const int f = b & 3, kk = b >> 2;
        const int k = kk * 32 + (l >> 4) * 8 + j;
        const int col = f * 16 + (l & 15);
        W2p[o] = f2bf(W2[k * C_DIM + col]);
    }
    if (o < n) cnt[o] = 0;
}

// ---------------------------------------------------------------------------
// FUSED MLP + rank, 3:1 block ratio. Blocks with (b&3)==3 run the atomic rank
// pass (24 edges/thread); the rest run the MFMA MLP (writes f32 hf).
// NOTE: MLP role must NOT early-return — all 4 waves cooperatively stage the
// W1p LDS slices (round-12 bug: a returned wave left 1/4 of LDS unwritten).
// ---------------------------------------------------------------------------
__global__ __launch_bounds__(256) void mlp_rank_kernel(
    const float* __restrict__ x,
    const ushort* __restrict__ W1p, const float* __restrict__ b1,
    const ushort* __restrict__ W2p, const float* __restrict__ b2,
    float* __restrict__ hf, int n,
    const int* __restrict__ col, int* __restrict__ cnt,
    int* __restrict__ rank, int e)
{
    __shared__ __align__(16) char smem[32768];   // used by MLP role only

    if ((blockIdx.x & 3) == 3) {
        // ---- rank role: 24 edges (3 int4-pairs) per thread ----
        const int base = ((blockIdx.x >> 2) * 256 + threadIdx.x) * 24;
        #pragma unroll
        for (int g = 0; g < 3; ++g) {
            const int i0 = base + g * 8;
            if (i0 + 7 < e) {
                const int4 ca = *(const int4*)&col[i0];
                const int4 cb = *(const int4*)&col[i0 + 4];
                const int r0 = atomicAdd(&cnt[ca.x], 1);
                const int r1 = atomicAdd(&cnt[ca.y], 1);
                const int r2 = atomicAdd(&cnt[ca.z], 1);
                const int r3 = atomicAdd(&cnt[ca.w], 1);
                const int r4 = atomicAdd(&cnt[cb.x], 1);
                const int r5 = atomicAdd(&cnt[cb.y], 1);
                const int r6 = atomicAdd(&cnt[cb.z], 1);
                const int r7 = atomicAdd(&cnt[cb.w], 1);
                *(int4*)&rank[i0]     = make_int4(r0, r1, r2, r3);
                *(int4*)&rank[i0 + 4] = make_int4(r4, r5, r6, r7);
            } else if (i0 < e) {
                for (int i = i0; i < e; ++i) rank[i] = atomicAdd(&cnt[col[i]], 1);
            }
        }
        return;
    }

    // ---- MLP role: bx = dense index over blocks with (b&3)!=3 ----
    const int bx = (blockIdx.x >> 2) * 3 + (blockIdx.x & 3);
    const int t = threadIdx.x;
    const int lane = t & 63;
    const int wv = t >> 6;
    const int ln15 = lane & 15;
    const int hi = lane >> 4;
    const long row0 = (long)bx * 64 + wv * 16;

    long arow = row0 + ln15;
    if (arow > (long)n - 1) arow = n - 1;
    const float4* xp = (const float4*)(x + arow * F_IN);

    f32x4 acc[16];
    #pragma unroll
    for (int f = 0; f < 16; ++f) acc[f] = (f32x4){0.f, 0.f, 0.f, 0.f};

    // stage W1p slice 0 (ALL waves participate)
    {
        const char* g = (const char*)(W1p);
        char* l = smem;
        #pragma unroll
        for (int j = 0; j < 4; ++j)
            GLOAD_LDS16(g + j * 4096 + wv * 1024 + lane * 16,
                        l + j * 4096 + wv * 1024);
    }
    __syncthreads();

    for (int ks = 0; ks < 16; ++ks) {
        if (ks < 15) {   // stage next slice into other buffer
            const char* g = (const char*)(W1p + (size_t)(ks + 1) * 8192);
            char* l = smem + ((ks + 1) & 1) * 16384;
            #pragma unroll
            for (int j = 0; j < 4; ++j)
                GLOAD_LDS16(g + j * 4096 + wv * 1024 + lane * 16,
                            l + j * 4096 + wv * 1024);
        }
        const float4 a0 = xp[ks * 8 + hi * 2];
        const float4 a1 = xp[ks * 8 + hi * 2 + 1];
        bf16x8 af;
        af[0] = (short)f2bf(a0.x); af[1] = (short)f2bf(a0.y);
        af[2] = (short)f2bf(a0.z); af[3] = (short)f2bf(a0.w);
        af[4] = (short)f2bf(a1.x); af[5] = (short)f2bf(a1.y);
        af[6] = (short)f2bf(a1.z); af[7] = (short)f2bf(a1.w);
        const ushort* wb = (const ushort*)(smem + (ks & 1) * 16384) + lane * 8;
        #pragma unroll
        for (int f = 0; f < 16; ++f) {
            const bf16x8 bfv = *(const bf16x8*)(wb + f * 512);
            acc[f] = __builtin_amdgcn_mfma_f32_16x16x32_bf16(af, bfv, acc[f], 0, 0, 0);
        }
        __syncthreads();
    }

    // h1 = relu(acc + b1) -> per-wave swizzled LDS tile (aliases staging bufs)
    char* hreg = smem + wv * 8192;
    #pragma unroll
    for (int f = 0; f < 16; ++f) {
        const int c = f * 16 + ln15;
        const float bias = b1[c];
        #pragma unroll
        for (int v = 0; v < 4; ++v) {
            const int r = hi * 4 + v;
            float val = acc[f][v] + bias;
            val = val > 0.f ? val : 0.f;
            const int pos = (r * 256 + c) * 2;
            *(short*)(hreg + (pos ^ ((r & 7) << 4))) = (short)f2bf(val);
        }
    }

    // GEMM2: [16x256] @ [256x64]
    f32x4 acc2[4];
    #pragma unroll
    for (int f = 0; f < 4; ++f) acc2[f] = (f32x4){0.f, 0.f, 0.f, 0.f};
    #pragma unroll
    for (int kk = 0; kk < 8; ++kk) {
        const int pos = (ln15 * 256 + kk * 32 + hi * 8) * 2;
        const bf16x8 a2 = *(const bf16x8*)(hreg + (pos ^ ((ln15 & 7) << 4)));
        #pragma unroll
        for (int f = 0; f < 4; ++f) {
            const bf16x8 b2f = *(const bf16x8*)&W2p[(kk * 4 + f) * 512 + lane * 8];
            acc2[f] = __builtin_amdgcn_mfma_f32_16x16x32_bf16(a2, b2f, acc2[f], 0, 0, 0);
        }
    }

    #pragma unroll
    for (int f = 0; f < 4; ++f) {
        const int c = f * 16 + ln15;
        const float bias = b2[c];
        #pragma unroll
        for (int v = 0; v < 4; ++v) {
            const long r = row0 + hi * 4 + v;
            if (r < n) hf[r * C_DIM + c] = acc2[f][v] + bias;
        }
    }
}

// ---------------------------------------------------------------------------
// Scan (1024 elems/block) + dinv fused
// ---------------------------------------------------------------------------
__global__ __launch_bounds__(256) void scan1_kernel(
    const int* __restrict__ cnt, int* __restrict__ rowptr, int* __restrict__ sums,
    float* __restrict__ dinv, int n)
{
    __shared__ int lds[256];
    const int t = threadIdx.x;
    const int base = blockIdx.x * 1024 + t * 4;
    int v[4];
    #pragma unroll
    for (int j = 0; j < 4; ++j) v[j] = (base + j < n) ? cnt[base + j] : 0;
    const int tsum = v[0] + v[1] + v[2] + v[3];
    lds[t] = tsum;
    __syncthreads();
    for (int o = 1; o < 256; o <<= 1) {
        const int add = (t >= o) ? lds[t - o] : 0;
        __syncthreads();
        lds[t] += add;
        __syncthreads();
    }
    int run = lds[t] - tsum;
    #pragma unroll
    for (int j = 0; j < 4; ++j) {
        if (base + j < n) {
            rowptr[base + j] = run;
            dinv[base + j] = rsqrtf((float)v[j] + 1.0f);   // +1 self-loop
        }
        run += v[j];
    }
    if (t == 255) sums[blockIdx.x] = lds[255];
}

__global__ __launch_bounds__(128) void scan2_kernel(int* __restrict__ sums, int nc)
{
    __shared__ int lds[128];
    const int t = threadIdx.x;
    const int v = (t < nc) ? sums[t] : 0;
    lds[t] = v;
    __syncthreads();
    for (int o = 1; o < 128; o <<= 1) {
        const int add = (t >= o) ? lds[t - o] : 0;
        __syncthreads();
        lds[t] += add;
        __syncthreads();
    }
    if (t < nc) sums[t] = lds[t] - v;
}

__global__ void scan3_kernel(int* __restrict__ rowptr, const int* __restrict__ sums, int n, int e)
{
    int i = blockIdx.x * 256 + threadIdx.x;
    if (i < n) rowptr[i] += sums[i >> 10];
    else if (i == n) rowptr[n] = e;
}

// ---------------------------------------------------------------------------
// FUSED fill (atomic-free, 8-edge ILP) + zsinit. Role by block range.
// ---------------------------------------------------------------------------
__global__ void fill_zs_kernel(const int* __restrict__ row, const int* __restrict__ col,
                               const int* __restrict__ rowptr, const int* __restrict__ rank,
                               int* __restrict__ csr_src, int e, int fill_blocks,
                               const float* __restrict__ hf, const float* __restrict__ dinv,
                               ushort* __restrict__ ah, ushort* __restrict__ zs, int n)
{
    if ((int)blockIdx.x < fill_blocks) {
        const int i0 = (blockIdx.x * 256 + threadIdx.x) * 8;
        if (i0 + 7 < e) {
            const int4 ca  = *(const int4*)&col[i0];
            const int4 cb  = *(const int4*)&col[i0 + 4];
            const int4 ka  = *(const int4*)&rank[i0];
            const int4 kb  = *(const int4*)&rank[i0 + 4];
            const int4 ra  = *(const int4*)&row[i0];
            const int4 rb  = *(const int4*)&row[i0 + 4];
            csr_src[rowptr[ca.x] + ka.x] = ra.x;
            csr_src[rowptr[ca.y] + ka.y] = ra.y;
            csr_src[rowptr[ca.z] + ka.z] = ra.z;
            csr_src[rowptr[ca.w] + ka.w] = ra.w;
            csr_src[rowptr[cb.x] + kb.x] = rb.x;
            csr_src[rowptr[cb.y] + kb.y] = rb.y;
            csr_src[rowptr[cb.z] + kb.z] = rb.z;
            csr_src[rowptr[cb.w] + kb.w] = rb.w;
        } else if (i0 < e) {
            for (int i = i0; i < e; ++i) csr_src[rowptr[col[i]] + rank[i]] = row[i];
        }
        return;
    }
    // zsinit role: 8 channels per thread
    const int i = ((int)blockIdx.x - fill_blocks) * 256 + threadIdx.x;
    if (i >= n * 8) return;
    const int node = i >> 3, part = i & 7;
    const float di = dinv[node];
    const long off = (long)node * C_DIM + part * 8;
    const float4 a = *(const float4*)&hf[off];
    const float4 b = *(const float4*)&hf[off + 4];
    uint4 z, ua;
    z.x = ((unsigned)f2bf(a.y * di) << 16) | f2bf(a.x * di);
    z.y = ((unsigned)f2bf(a.w * di) << 16) | f2bf(a.z * di);
    z.z = ((unsigned)f2bf(b.y * di) << 16) | f2bf(b.x * di);
    z.w = ((unsigned)f2bf(b.w * di) << 16) | f2bf(b.z * di);
    ua.x = ((unsigned)f2bf(a.y * ALPHA) << 16) | f2bf(a.x * ALPHA);
    ua.y = ((unsigned)f2bf(a.w * ALPHA) << 16) | f2bf(a.z * ALPHA);
    ua.z = ((unsigned)f2bf(b.y * ALPHA) << 16) | f2bf(b.x * ALPHA);
    ua.w = ((unsigned)f2bf(b.w * ALPHA) << 16) | f2bf(b.z * ALPHA);
    *(uint4*)&zs[off] = z;
    *(uint4*)&ah[off] = ua;
}

// ---------------------------------------------------------------------------
// APPNP step (round-8 proven): one wave per node; slot s = lane>>3 (8 slots x
// 16B), guarded 4-deep row pipeline. Final iteration fuses log-softmax.
// ---------------------------------------------------------------------------
__global__ __launch_bounds__(256) void gather8_kernel(
    const int* __restrict__ rowptr, const int* __restrict__ csr_src,
    const float* __restrict__ dinv, const ushort* __restrict__ ah,
    const ushort* __restrict__ zs_in, ushort* __restrict__ zs_out,
    float* __restrict__ out, int n, int final_it)
{
    const int node = (blockIdx.x * 256 + threadIdx.x) >> 6;
    if (node >= n) return;
    const int lane = threadIdx.x & 63;
    const int s = lane >> 3;
    const int cg = lane & 7;

    const int p0 = rowptr[node];
    const int p1 = rowptr[node + 1];

    float acc[8];
    #pragma unroll
    for (int c = 0; c < 8; ++c) acc[c] = 0.f;

    if (s == 0) {  // self-loop: 8 lanes cover own 128B row
        const uint4 u = *(const uint4*)&zs_in[(long)node * C_DIM + cg * 8];
        ACC8(u);
    }

    if (p0 < p1) {
        int p = p0 + s;
        int c0 = (p      < p1) ? csr_src[p]      : -1;
        int c1 = (p +  8 < p1) ? csr_src[p +  8] : -1;
        int c2 = (p + 16 < p1) ? csr_src[p + 16] : -1;
        int c3 = (p + 24 < p1) ? csr_src[p + 24] : -1;
        while (c0 >= 0) {
            uint4 u0, u1, u2, u3;
            u0 = *(const uint4*)&zs_in[(long)c0 * C_DIM + cg * 8];
            if (c1 >= 0) u1 = *(const uint4*)&zs_in[(long)c1 * C_DIM + cg * 8];
            if (c2 >= 0) u2 = *(const uint4*)&zs_in[(long)c2 * C_DIM + cg * 8];
            if (c3 >= 0) u3 = *(const uint4*)&zs_in[(long)c3 * C_DIM + cg * 8];
            p += 32;
            const int n0 = (p      < p1) ? csr_src[p]      : -1;
            const int n1 = (p +  8 < p1) ? csr_src[p +  8] : -1;
            const int n2 = (p + 16 < p1) ? csr_src[p + 16] : -1;
            const int n3 = (p + 24 < p1) ? csr_src[p + 24] : -1;
            ACC8(u0);
            if (c1 >= 0) ACC8(u1);
            if (c2 >= 0) ACC8(u2);
            if (c3 >= 0) ACC8(u3);
            c0 = n0; c1 = n1; c2 = n2; c3 = n3;
        }
    }

    #pragma unroll
    for (int c = 0; c < 8; ++c) {
        acc[c] += __shfl_xor(acc[c], 8, 64);
        acc[c] += __shfl_xor(acc[c], 16, 64);
        acc[c] += __shfl_xor(acc[c], 32, 64);
    }

    if (s == 0) {
        const float di = dinv[node];
        const long off = (long)node * C_DIM + cg * 8;
        const uint4 ua = *(const uint4*)&ah[off];
        const float w = (1.0f - ALPHA) * di;
        float z[8];
        z[0] = w * acc[0] + bflo(ua.x);
        z[1] = w * acc[1] + bfhi(ua.x);
        z[2] = w * acc[2] + bflo(ua.y);
        z[3] = w * acc[3] + bfhi(ua.y);
        z[4] = w * acc[4] + bflo(ua.z);
        z[5] = w * acc[5] + bfhi(ua.z);
        z[6] = w * acc[6] + bflo(ua.w);
        z[7] = w * acc[7] + bfhi(ua.w);
        if (!final_it) {
            uint4 o;
            o.x = ((unsigned)f2bf(z[1] * di) << 16) | f2bf(z[0] * di);
            o.y = ((unsigned)f2bf(z[3] * di) << 16) | f2bf(z[2] * di);
            o.z = ((unsigned)f2bf(z[5] * di) << 16) | f2bf(z[4] * di);
            o.w = ((unsigned)f2bf(z[7] * di) << 16) | f2bf(z[6] * di);
            *(uint4*)&zs_out[off] = o;
        } else {
            // fused log-softmax across the 8 s==0 lanes of this node
            float m = z[0];
            #pragma unroll
            for (int j = 1; j < 8; ++j) m = fmaxf(m, z[j]);
            m = fmaxf(m, __shfl_xor(m, 1, 64));
            m = fmaxf(m, __shfl_xor(m, 2, 64));
            m = fmaxf(m, __shfl_xor(m, 4, 64));
            float se = 0.f;
            #pragma unroll
            for (int j = 0; j < 8; ++j) se += expf(z[j] - m);
            se += __shfl_xor(se, 1, 64);
            se += __shfl_xor(se, 2, 64);
            se += __shfl_xor(se, 4, 64);
            const float ls = m + logf(se);
            *(float4*)&out[off]     = make_float4(z[0] - ls, z[1] - ls, z[2] - ls, z[3] - ls);
            *(float4*)&out[off + 4] = make_float4(z[4] - ls, z[5] - ls, z[6] - ls, z[7] - ls);
        }
    }
}

// ---------------------------------------------------------------------------
extern "C" void kernel_launch(void* const* d_in, const int* in_sizes, int n_in,
                              void* d_out, int out_size, void* d_ws, size_t ws_size,
                              hipStream_t stream)
{
    const float* x  = (const float*)d_in[0];
    const int* ei   = (const int*)d_in[1];
    const float* W1 = (const float*)d_in[2];
    const float* b1 = (const float*)d_in[3];
    const float* W2 = (const float*)d_in[4];
    const float* b2 = (const float*)d_in[5];
    float* out = (float*)d_out;

    const int N = in_sizes[0] / F_IN;       // 100000
    const int E = in_sizes[1] / 2;          // 3200000
    const int* row = ei;                    // source
    const int* col = ei + E;                // target

    // workspace layout
    ushort* ah     = (ushort*)d_ws;                           // N*64 bf16 (alpha*h)
    ushort* zs_a   = ah + (size_t)N * C_DIM;                  // N*64 bf16
    ushort* zs_b   = zs_a + (size_t)N * C_DIM;                // N*64 bf16
    float*  hf     = (float*)(zs_b + (size_t)N * C_DIM);      // N*64 f32
    float*  dinv   = hf + (size_t)N * C_DIM;                  // N
    int*    cnt    = (int*)(dinv + N);                        // N
    int*    rowptr = cnt + N;                                 // N+16 (padded)
    int*    rank   = rowptr + N + 16;                         // E
    int*    csr_src = rank + E;                               // E (+4 pad)
    int*    sums   = csr_src + E + 4;                         // 128
    ushort* W1p    = (ushort*)(sums + 128);                   // 131072
    ushort* W2p    = W1p + 131072;                            // 16384

    const int mlp_blocks  = (N + 63) / 64;                    // 1563
    const int rank_blocks = (E + 24 * 256 - 1) / (24 * 256);  // 521
    // 3:1 interleave: need 4*max(ceil(mlp/3), rank_blocks) block groups
    const int groups = ((mlp_blocks + 2) / 3 > rank_blocks) ? (mlp_blocks + 2) / 3 : rank_blocks;
    const int fused_blocks = groups * 4;
    const int nchunks = (N + 1023) / 1024;

    // 1. weight prep + cnt zero
    prep_kernel<<<512, 256, 0, stream>>>(W1, W1p, W2, W2p, cnt, N);

    // 2. FUSED: MLP (3/4 of blocks, writes hf) || rank (1/4, atomics)
    mlp_rank_kernel<<<fused_blocks, 256, 0, stream>>>(x, W1p, b1, W2p, b2, hf, N,
                                                      col, cnt, rank, E);

    // 3. scans (dinv, rowptr)
    scan1_kernel<<<nchunks, 256, 0, stream>>>(cnt, rowptr, sums, dinv, N);
    scan2_kernel<<<1, 128, 0, stream>>>(sums, nchunks);
    scan3_kernel<<<(N + 256) / 256, 256, 0, stream>>>(rowptr, sums, N, E);

    // 4. FUSED: fill (atomic-free) || zsinit (ah, zs_a from hf)
    const int fill_blocks = (E / 8 + 255) / 256;
    const int zs_blocks = (N * 8 + 255) / 256;
    fill_zs_kernel<<<fill_blocks + zs_blocks, 256, 0, stream>>>(
        row, col, rowptr, rank, csr_src, E, fill_blocks,
        hf, dinv, ah, zs_a, N);

    // 5. APPNP iterations (ping-pong bf16; final fuses log-softmax -> out)
    const int gblk = (N + 3) / 4;   // one wave per node
    for (int it = 0; it < K_STEPS; ++it) {
        const ushort* in = (it & 1) ? zs_b : zs_a;
        ushort* outb     = (it & 1) ? zs_a : zs_b;
        gather8_kernel<<<gblk, 256, 0, stream>>>(rowptr, csr_src, dinv, ah,
                                                 in, outb, out, N,
                                                 it == K_STEPS - 1 ? 1 : 0);
    }
}